// Round 1
// baseline (1616.230 us; speedup 1.0000x reference)
//
#include <hip/hip_runtime.h>
#include <cstdint>
#include <cstddef>

// ---------------------------------------------------------------------------
// AFMADE block: 16-step autoregressive inversion of two 3-layer MADE MLPs.
// D=16, H=1024, B=2048.
// Design:
//   prep_*   : bake mask * g * v/||v|| into bf16 weights (once per launch)
//   init_h0  : h0 = elu(b0)  (y starts at 0)
//   loop 16x : gemm_l1 (MFMA bf16, h1 = elu(h0 @ W1^T + b1), both nets)
//              step_kernel (layer2 + recurrence + layer0 -> next h0)
// ---------------------------------------------------------------------------

#define Dd 16
#define Hh 1024
#define Bb 2048
#define EPSV 1e-12f

typedef unsigned short u16;
typedef __attribute__((ext_vector_type(4))) float f32x4;
typedef __attribute__((ext_vector_type(8))) short s16x8;
typedef __attribute__((ext_vector_type(4))) u16 u16x4;
typedef __attribute__((ext_vector_type(8))) u16 u16x8;

__device__ __forceinline__ u16 f2bf(float f) {
  union { float f; unsigned u; } v; v.f = f;
  unsigned u = v.u;
  unsigned r = (u + 0x7fffu + ((u >> 16) & 1u)) >> 16;  // RNE
  return (u16)r;
}
__device__ __forceinline__ float bf2f(u16 u) {
  union { unsigned u; float f; } v; v.u = ((unsigned)u) << 16;
  return v.f;
}
__device__ __forceinline__ float elu(float a) {
  return a > 0.f ? a : __expf(a) - 1.f;
}
__device__ __forceinline__ void gl_lds16(const u16* g, u16* l) {
  __builtin_amdgcn_global_load_lds(
      (const __attribute__((address_space(1))) void*)g,
      (__attribute__((address_space(3))) void*)l, 16, 0, 0);
}

// --------------------------- weight prep -----------------------------------

// W0[net][j][d] = m0 * g*v/||v||, m0: (j%15) >= d. One thread per (net,j).
__global__ __launch_bounds__(256) void prep_w0(
    const float* __restrict__ v_mu, const float* __restrict__ g_mu,
    const float* __restrict__ v_lv, const float* __restrict__ g_lv,
    u16* __restrict__ W0) {
  int idx = blockIdx.x * 256 + threadIdx.x;  // 0..2047
  int net = idx >> 10, j = idx & 1023;
  const float* v = (net ? v_lv : v_mu) + j * Dd;
  float vv[16]; float ss = 0.f;
  for (int k = 0; k < 16; ++k) { vv[k] = v[k]; ss += vv[k] * vv[k]; }
  float sc = ((net ? g_lv : g_mu)[j]) * rsqrtf(ss);
  int jm = j % 15;
  u16* o = W0 + idx * 16;
  for (int k = 0; k < 16; ++k) o[k] = f2bf((jm >= k) ? sc * vv[k] : 0.f);
}

// W1[net][j][k] = m1 * g*v/||v||, m1: (j%15) >= (k%15). One wave per row.
__global__ __launch_bounds__(256) void prep_w1(
    const float* __restrict__ v_mu, const float* __restrict__ g_mu,
    const float* __restrict__ v_lv, const float* __restrict__ g_lv,
    u16* __restrict__ W1) {
  int wid = blockIdx.x * 4 + (threadIdx.x >> 6);  // 0..2047
  int l = threadIdx.x & 63;
  int net = wid >> 10, j = wid & 1023;
  const float* v = (net ? v_lv : v_mu) + (size_t)j * Hh;
  f32x4 val[4]; float ss = 0.f;
  for (int ii = 0; ii < 4; ++ii) {
    val[ii] = *(const f32x4*)(v + ii * 256 + 4 * l);
    ss += val[ii][0]*val[ii][0] + val[ii][1]*val[ii][1]
        + val[ii][2]*val[ii][2] + val[ii][3]*val[ii][3];
  }
  for (int s = 32; s; s >>= 1) ss += __shfl_xor(ss, s);
  float sc = ((net ? g_lv : g_mu)[j]) * rsqrtf(ss);
  int jm = j % 15;
  u16* o = W1 + (size_t)wid * Hh;
  for (int ii = 0; ii < 4; ++ii) {
    int k0 = ii * 256 + 4 * l;
    u16x4 w;
    for (int t = 0; t < 4; ++t) {
      int k = k0 + t;
      w[t] = f2bf((jm >= (k % 15)) ? sc * val[ii][t] : 0.f);
    }
    *(u16x4*)(o + k0) = w;
  }
}

// W2[net][i][k] = m2 * g*v/||v||, m2: i > (k%15). One wave per row (32 rows).
__global__ __launch_bounds__(256) void prep_w2(
    const float* __restrict__ v_mu, const float* __restrict__ g_mu,
    const float* __restrict__ v_lv, const float* __restrict__ g_lv,
    u16* __restrict__ W2) {
  int wid = blockIdx.x * 4 + (threadIdx.x >> 6);  // 0..31
  int l = threadIdx.x & 63;
  int net = wid >> 4, i = wid & 15;
  const float* v = (net ? v_lv : v_mu) + (size_t)i * Hh;
  f32x4 val[4]; float ss = 0.f;
  for (int ii = 0; ii < 4; ++ii) {
    val[ii] = *(const f32x4*)(v + ii * 256 + 4 * l);
    ss += val[ii][0]*val[ii][0] + val[ii][1]*val[ii][1]
        + val[ii][2]*val[ii][2] + val[ii][3]*val[ii][3];
  }
  for (int s = 32; s; s >>= 1) ss += __shfl_xor(ss, s);
  float sc = ((net ? g_lv : g_mu)[i]) * rsqrtf(ss);
  u16* o = W2 + (size_t)wid * Hh;
  for (int ii = 0; ii < 4; ++ii) {
    int k0 = ii * 256 + 4 * l;
    u16x4 w;
    for (int t = 0; t < 4; ++t) {
      int k = k0 + t;
      w[t] = f2bf((i > (k % 15)) ? sc * val[ii][t] : 0.f);
    }
    *(u16x4*)(o + k0) = w;
  }
}

// --------------------------- init ------------------------------------------

__global__ __launch_bounds__(256) void zero_y(float* __restrict__ y) {
  y[blockIdx.x * 256 + threadIdx.x] = 0.f;
}

// h0[net][b][j] = elu(b0[net][j])  (y == 0 at step 0)
__global__ __launch_bounds__(256) void init_h0(
    const float* __restrict__ b0_mu, const float* __restrict__ b0_lv,
    u16* __restrict__ h0) {
  int idx = blockIdx.x * 256 + threadIdx.x;  // over 2*2048*1024
  int j = idx & 1023;
  int net = idx >> 21;
  float b = (net ? b0_lv : b0_mu)[j];
  h0[idx] = f2bf(elu(b));
}

// --------------------------- layer 1 GEMM ----------------------------------
// h1[net][m][n] = elu(b1[net][n] + sum_k h0[net][m][k] * W1[net][n][k])
// M=2048, N=1024, K=1024 per net. Tile 128x128, BK=64, 8 waves (2x4),
// wave tile 64x32 (4x2 frags of 16x16), mfma_f32_16x16x32_bf16.
// grid = 2 nets * 16 mtiles * 8 ntiles = 256 blocks, 512 threads.
__global__ __launch_bounds__(512) void gemm_l1(
    const u16* __restrict__ h0, const u16* __restrict__ W1,
    const float* __restrict__ b1_mu, const float* __restrict__ b1_lv,
    u16* __restrict__ h1) {
  __shared__ u16 sA[128 * 64];
  __shared__ u16 sB[128 * 64];
  int bid = blockIdx.x;
  int net = bid >> 7;
  int t = bid & 127;
  int mt = t >> 3, nt = t & 7;
  int m0 = mt * 128, n0 = nt * 128;
  const u16* A = h0 + (size_t)net * (Bb * Hh);
  const u16* Bm = W1 + (size_t)net * (Hh * Hh);
  int tid = threadIdx.x;
  int l = tid & 63, w = tid >> 6;
  int wr = w >> 2, wc = w & 3;      // 2 x 4 wave grid
  int lr = l & 15, lk = l >> 4;     // lane row/col, k-block
  f32x4 acc[4][2] = {};

  for (int kt = 0; kt < 16; ++kt) {
    int kb = kt * 64;
    __syncthreads();
    for (int c = 0; c < 2; ++c) {
      int q = c * 512 + tid;          // 16B chunk id, 0..1023
      int row = q >> 3, cc = q & 7;
      gl_lds16(A + (size_t)(m0 + row) * Hh + kb + cc * 8, sA + q * 8);
      gl_lds16(Bm + (size_t)(n0 + row) * Hh + kb + cc * 8, sB + q * 8);
    }
    __syncthreads();
    for (int kk = 0; kk < 2; ++kk) {
      int ko = kk * 32 + lk * 8;
      s16x8 af[4], bfr[2];
      for (int mi = 0; mi < 4; ++mi)
        af[mi] = *(const s16x8*)(sA + (wr * 64 + mi * 16 + lr) * 64 + ko);
      for (int ni = 0; ni < 2; ++ni)
        bfr[ni] = *(const s16x8*)(sB + (wc * 32 + ni * 16 + lr) * 64 + ko);
      for (int mi = 0; mi < 4; ++mi)
        for (int ni = 0; ni < 2; ++ni)
          acc[mi][ni] = __builtin_amdgcn_mfma_f32_16x16x32_bf16(
              af[mi], bfr[ni], acc[mi][ni], 0, 0, 0);
    }
  }

  const float* b1 = net ? b1_lv : b1_mu;
  u16* C = h1 + (size_t)net * (Bb * Hh);
  for (int ni = 0; ni < 2; ++ni) {
    int col = n0 + wc * 32 + ni * 16 + lr;
    float bias = b1[col];
    for (int mi = 0; mi < 4; ++mi) {
      for (int r = 0; r < 4; ++r) {
        int row = m0 + wr * 64 + mi * 16 + lk * 4 + r;
        C[(size_t)row * Hh + col] = f2bf(elu(acc[mi][ni][r] + bias));
      }
    }
  }
}

// --------------------------- layer2 + recur + layer0 -----------------------
// Per block: 16 batch rows. Phase A: out = h1 @ W2^T + b2 (W2 in LDS,
// wave-reduce dots). Phase B: y = (x-mu)/(exp(0.5*lv)+eps); final-step
// outputs. Phase C: h0' = elu(y @ W0^T + b0).
__global__ __launch_bounds__(256) void step_kernel(
    const u16* __restrict__ h1, const u16* __restrict__ W2,
    const float* __restrict__ b2_mu, const float* __restrict__ b2_lv,
    const u16* __restrict__ W0,
    const float* __restrict__ b0_mu, const float* __restrict__ b0_lv,
    const float* __restrict__ x, float* __restrict__ y,
    u16* __restrict__ h0, float* __restrict__ out, int last) {
  __shared__ u16 sW2[2 * 16 * Hh];   // 64 KiB
  __shared__ float sOut[16][32];
  __shared__ float sY[16][17];
  int tid = threadIdx.x;
  for (int i = 0; i < 16; ++i) {
    int e = tid + i * 256;
    *(u16x8*)(sW2 + e * 8) = *(const u16x8*)(W2 + e * 8);
  }
  __syncthreads();
  int l = tid & 63, w = tid >> 6;
  int b0g = blockIdx.x * 16;

  for (int rr = 0; rr < 4; ++rr) {
    int bl = w * 4 + rr;
    int b = b0g + bl;
    float hreg[2][16];
    for (int net = 0; net < 2; ++net) {
      const u16* hp = h1 + (size_t)net * (Bb * Hh) + (size_t)b * Hh;
      for (int ii = 0; ii < 4; ++ii) {
        u16x4 hv = *(const u16x4*)(hp + ii * 256 + 4 * l);
        for (int tt = 0; tt < 4; ++tt) hreg[net][ii * 4 + tt] = bf2f(hv[tt]);
      }
    }
    for (int o = 0; o < 32; ++o) {
      int net = o >> 4, ir = o & 15;
      const u16* wp = sW2 + net * (16 * Hh) + ir * Hh;
      float p = 0.f;
      for (int ii = 0; ii < 4; ++ii) {
        u16x4 wv = *(const u16x4*)(wp + ii * 256 + 4 * l);
        for (int tt = 0; tt < 4; ++tt) p += hreg[net][ii * 4 + tt] * bf2f(wv[tt]);
      }
      for (int s = 32; s; s >>= 1) p += __shfl_xor(p, s);
      if (l == 0) sOut[bl][o] = p + (net ? b2_lv : b2_mu)[ir];
    }
  }
  __syncthreads();
  {
    int bl = tid >> 4, d = tid & 15;
    int b = b0g + bl;
    float mu = sOut[bl][d];
    float ls = 0.5f * sOut[bl][16 + d];
    float yn = (x[b * 16 + d] - mu) / (__expf(ls) + EPSV);
    y[b * 16 + d] = yn;
    sY[bl][d] = yn;
    if (last) {
      out[b * 16 + d] = yn;
      if (d == 0) {
        float s = 0.f;
        for (int j2 = 0; j2 < 16; ++j2) s += 0.5f * sOut[bl][16 + j2];
        out[Bb * 16 + b] = s;
      }
    }
  }
  __syncthreads();
  if (!last) {
    for (int it = 0; it < 8; ++it) {
      int jj = it * 256 + tid;
      int net = jj >> 10, j = jj & 1023;
      u16x8 wa = *(const u16x8*)(W0 + jj * 16);
      u16x8 wb = *(const u16x8*)(W0 + jj * 16 + 8);
      float wk[16];
      for (int tt = 0; tt < 8; ++tt) { wk[tt] = bf2f(wa[tt]); wk[8 + tt] = bf2f(wb[tt]); }
      float bias = (net ? b0_lv : b0_mu)[j];
      u16* hp = h0 + (size_t)net * (Bb * Hh) + j;
      for (int bl = 0; bl < 16; ++bl) {
        float a = bias;
        for (int k = 0; k < 16; ++k) a += sY[bl][k] * wk[k];
        hp[(size_t)(b0g + bl) * Hh] = f2bf(elu(a));
      }
    }
  }
}

// --------------------------- launch ----------------------------------------

extern "C" void kernel_launch(void* const* d_in, const int* in_sizes, int n_in,
                              void* d_out, int out_size, void* d_ws, size_t ws_size,
                              hipStream_t stream) {
  const float* x     = (const float*)d_in[0];
  const float* mu_v0 = (const float*)d_in[1];
  const float* mu_g0 = (const float*)d_in[2];
  const float* mu_b0 = (const float*)d_in[3];
  const float* mu_v1 = (const float*)d_in[4];
  const float* mu_g1 = (const float*)d_in[5];
  const float* mu_b1 = (const float*)d_in[6];
  const float* mu_v2 = (const float*)d_in[7];
  const float* mu_g2 = (const float*)d_in[8];
  const float* mu_b2 = (const float*)d_in[9];
  const float* lv_v0 = (const float*)d_in[10];
  const float* lv_g0 = (const float*)d_in[11];
  const float* lv_b0 = (const float*)d_in[12];
  const float* lv_v1 = (const float*)d_in[13];
  const float* lv_g1 = (const float*)d_in[14];
  const float* lv_b1 = (const float*)d_in[15];
  const float* lv_v2 = (const float*)d_in[16];
  const float* lv_g2 = (const float*)d_in[17];
  const float* lv_b2 = (const float*)d_in[18];

  char* ws = (char*)d_ws;
  u16*   W1 = (u16*)(ws);                          // 2*1024*1024*2 = 4 MiB
  u16*   W0 = (u16*)(ws + (4u << 20));             // 64 KiB
  u16*   W2 = (u16*)(ws + (4u << 20) + 65536);     // 64 KiB
  u16*   h0 = (u16*)(ws + (4u << 20) + 131072);    // 8 MiB
  u16*   h1 = (u16*)(ws + (12u << 20) + 131072);   // 8 MiB
  float* yb = (float*)(ws + (20u << 20) + 131072); // 128 KiB

  zero_y<<<128, 256, 0, stream>>>(yb);
  prep_w0<<<8, 256, 0, stream>>>(mu_v0, mu_g0, lv_v0, lv_g0, W0);
  prep_w1<<<512, 256, 0, stream>>>(mu_v1, mu_g1, lv_v1, lv_g1, W1);
  prep_w2<<<8, 256, 0, stream>>>(mu_v2, mu_g2, lv_v2, lv_g2, W2);
  init_h0<<<16384, 256, 0, stream>>>(mu_b0, lv_b0, h0);

  for (int s = 0; s < 16; ++s) {
    gemm_l1<<<256, 512, 0, stream>>>(h0, W1, mu_b1, lv_b1, h1);
    step_kernel<<<128, 256, 0, stream>>>(h1, W2, mu_b2, lv_b2, W0, mu_b0,
                                         lv_b0, x, yb, h0, (float*)d_out,
                                         s == 15 ? 1 : 0);
  }
}

// Round 2
// 716.466 us; speedup vs baseline: 2.2558x; 2.2558x over previous
//
#include <hip/hip_runtime.h>
#include <cstdint>
#include <cstddef>

// ---------------------------------------------------------------------------
// AFMADE block: 16-step autoregressive inversion of two 3-layer MADE MLPs.
// D=16, H=1024, B=2048.
//   prep_*  : bake mask * g * v/||v|| into bf16 weights (once per launch)
//   init_h0 : h0 = elu(b0)  (y starts at 0)
//   loop 16x: gemm_l1 (MFMA bf16, h1 = elu(h0 @ W1^T + b1), both nets)
//             step2   (layer2 + recurrence + layer0 -> next h0; 2 rows/block)
// ---------------------------------------------------------------------------

#define Dd 16
#define Hh 1024
#define Bb 2048
#define EPSV 1e-12f

typedef unsigned short u16;
typedef __attribute__((ext_vector_type(4))) float f32x4;
typedef __attribute__((ext_vector_type(8))) short s16x8;
typedef __attribute__((ext_vector_type(4))) u16 u16x4;
typedef __attribute__((ext_vector_type(8))) u16 u16x8;

__device__ __forceinline__ u16 f2bf(float f) {
  union { float f; unsigned u; } v; v.f = f;
  unsigned u = v.u;
  unsigned r = (u + 0x7fffu + ((u >> 16) & 1u)) >> 16;  // RNE
  return (u16)r;
}
__device__ __forceinline__ float bf2f(u16 u) {
  union { unsigned u; float f; } v; v.u = ((unsigned)u) << 16;
  return v.f;
}
__device__ __forceinline__ float elu(float a) {
  return a > 0.f ? a : __expf(a) - 1.f;
}
__device__ __forceinline__ void gl_lds16(const u16* g, u16* l) {
  __builtin_amdgcn_global_load_lds(
      (const __attribute__((address_space(1))) void*)g,
      (__attribute__((address_space(3))) void*)l, 16, 0, 0);
}

// --------------------------- weight prep -----------------------------------

// W0[net][j][d] = m0 * g*v/||v||, m0: (j%15) >= d. One thread per (net,j).
__global__ __launch_bounds__(256) void prep_w0(
    const float* __restrict__ v_mu, const float* __restrict__ g_mu,
    const float* __restrict__ v_lv, const float* __restrict__ g_lv,
    u16* __restrict__ W0) {
  int idx = blockIdx.x * 256 + threadIdx.x;  // 0..2047
  int net = idx >> 10, j = idx & 1023;
  const float* v = (net ? v_lv : v_mu) + j * Dd;
  float vv[16]; float ss = 0.f;
  for (int k = 0; k < 16; ++k) { vv[k] = v[k]; ss += vv[k] * vv[k]; }
  float sc = ((net ? g_lv : g_mu)[j]) * rsqrtf(ss);
  int jm = j % 15;
  u16* o = W0 + idx * 16;
  for (int k = 0; k < 16; ++k) o[k] = f2bf((jm >= k) ? sc * vv[k] : 0.f);
}

// W1[net][j][k] = m1 * g*v/||v||, m1: (j%15) >= (k%15). One wave per row.
__global__ __launch_bounds__(256) void prep_w1(
    const float* __restrict__ v_mu, const float* __restrict__ g_mu,
    const float* __restrict__ v_lv, const float* __restrict__ g_lv,
    u16* __restrict__ W1) {
  int wid = blockIdx.x * 4 + (threadIdx.x >> 6);  // 0..2047
  int l = threadIdx.x & 63;
  int net = wid >> 10, j = wid & 1023;
  const float* v = (net ? v_lv : v_mu) + (size_t)j * Hh;
  f32x4 val[4]; float ss = 0.f;
  for (int ii = 0; ii < 4; ++ii) {
    val[ii] = *(const f32x4*)(v + ii * 256 + 4 * l);
    ss += val[ii][0]*val[ii][0] + val[ii][1]*val[ii][1]
        + val[ii][2]*val[ii][2] + val[ii][3]*val[ii][3];
  }
  for (int s = 32; s; s >>= 1) ss += __shfl_xor(ss, s);
  float sc = ((net ? g_lv : g_mu)[j]) * rsqrtf(ss);
  int jm = j % 15;
  u16* o = W1 + (size_t)wid * Hh;
  for (int ii = 0; ii < 4; ++ii) {
    int k0 = ii * 256 + 4 * l;
    u16x4 w;
    for (int t = 0; t < 4; ++t) {
      int k = k0 + t;
      w[t] = f2bf((jm >= (k % 15)) ? sc * val[ii][t] : 0.f);
    }
    *(u16x4*)(o + k0) = w;
  }
}

// W2[net][i][k] = m2 * g*v/||v||, m2: i > (k%15). One wave per row (32 rows).
__global__ __launch_bounds__(256) void prep_w2(
    const float* __restrict__ v_mu, const float* __restrict__ g_mu,
    const float* __restrict__ v_lv, const float* __restrict__ g_lv,
    u16* __restrict__ W2) {
  int wid = blockIdx.x * 4 + (threadIdx.x >> 6);  // 0..31
  int l = threadIdx.x & 63;
  int net = wid >> 4, i = wid & 15;
  const float* v = (net ? v_lv : v_mu) + (size_t)i * Hh;
  f32x4 val[4]; float ss = 0.f;
  for (int ii = 0; ii < 4; ++ii) {
    val[ii] = *(const f32x4*)(v + ii * 256 + 4 * l);
    ss += val[ii][0]*val[ii][0] + val[ii][1]*val[ii][1]
        + val[ii][2]*val[ii][2] + val[ii][3]*val[ii][3];
  }
  for (int s = 32; s; s >>= 1) ss += __shfl_xor(ss, s);
  float sc = ((net ? g_lv : g_mu)[i]) * rsqrtf(ss);
  u16* o = W2 + (size_t)wid * Hh;
  for (int ii = 0; ii < 4; ++ii) {
    int k0 = ii * 256 + 4 * l;
    u16x4 w;
    for (int t = 0; t < 4; ++t) {
      int k = k0 + t;
      w[t] = f2bf((i > (k % 15)) ? sc * val[ii][t] : 0.f);
    }
    *(u16x4*)(o + k0) = w;
  }
}

// --------------------------- init ------------------------------------------

// h0[net][b][j] = elu(b0[net][j])  (y == 0 at step 0)
__global__ __launch_bounds__(256) void init_h0(
    const float* __restrict__ b0_mu, const float* __restrict__ b0_lv,
    u16* __restrict__ h0) {
  int idx = blockIdx.x * 256 + threadIdx.x;  // over 2*2048*1024
  int j = idx & 1023;
  int net = idx >> 21;
  float b = (net ? b0_lv : b0_mu)[j];
  h0[idx] = f2bf(elu(b));
}

// --------------------------- layer 1 GEMM ----------------------------------
// h1[net][m][n] = elu(b1[net][n] + sum_k h0[net][m][k] * W1[net][n][k])
// M=2048, N=1024, K=1024 per net. Tile 128x128, BK=64, 8 waves (2x4),
// wave tile 64x32 (4x2 frags of 16x16), mfma_f32_16x16x32_bf16.
// grid = 2 nets * 16 mtiles * 8 ntiles = 256 blocks, 512 threads.
__global__ __launch_bounds__(512) void gemm_l1(
    const u16* __restrict__ h0, const u16* __restrict__ W1,
    const float* __restrict__ b1_mu, const float* __restrict__ b1_lv,
    u16* __restrict__ h1) {
  __shared__ u16 sA[128 * 64];
  __shared__ u16 sB[128 * 64];
  int bid = blockIdx.x;
  int net = bid >> 7;
  int t = bid & 127;
  int mt = t >> 3, nt = t & 7;
  int m0 = mt * 128, n0 = nt * 128;
  const u16* A = h0 + (size_t)net * (Bb * Hh);
  const u16* Bm = W1 + (size_t)net * (Hh * Hh);
  int tid = threadIdx.x;
  int l = tid & 63, w = tid >> 6;
  int wr = w >> 2, wc = w & 3;      // 2 x 4 wave grid
  int lr = l & 15, lk = l >> 4;     // lane row/col, k-block
  f32x4 acc[4][2] = {};

  for (int kt = 0; kt < 16; ++kt) {
    int kb = kt * 64;
    __syncthreads();
    for (int c = 0; c < 2; ++c) {
      int q = c * 512 + tid;          // 16B chunk id, 0..1023
      int row = q >> 3, cc = q & 7;
      gl_lds16(A + (size_t)(m0 + row) * Hh + kb + cc * 8, sA + q * 8);
      gl_lds16(Bm + (size_t)(n0 + row) * Hh + kb + cc * 8, sB + q * 8);
    }
    __syncthreads();
    for (int kk = 0; kk < 2; ++kk) {
      int ko = kk * 32 + lk * 8;
      s16x8 af[4], bfr[2];
      for (int mi = 0; mi < 4; ++mi)
        af[mi] = *(const s16x8*)(sA + (wr * 64 + mi * 16 + lr) * 64 + ko);
      for (int ni = 0; ni < 2; ++ni)
        bfr[ni] = *(const s16x8*)(sB + (wc * 32 + ni * 16 + lr) * 64 + ko);
      for (int mi = 0; mi < 4; ++mi)
        for (int ni = 0; ni < 2; ++ni)
          acc[mi][ni] = __builtin_amdgcn_mfma_f32_16x16x32_bf16(
              af[mi], bfr[ni], acc[mi][ni], 0, 0, 0);
    }
  }

  const float* b1 = net ? b1_lv : b1_mu;
  u16* C = h1 + (size_t)net * (Bb * Hh);
  for (int ni = 0; ni < 2; ++ni) {
    int col = n0 + wc * 32 + ni * 16 + lr;
    float bias = b1[col];
    for (int mi = 0; mi < 4; ++mi) {
      for (int r = 0; r < 4; ++r) {
        int row = m0 + wr * 64 + mi * 16 + lk * 4 + r;
        C[(size_t)row * Hh + col] = f2bf(elu(acc[mi][ni][r] + bias));
      }
    }
  }
}

// --------------------------- layer2 + recur + layer0 -----------------------
// 2 batch rows per block, 1024 blocks x 256 threads (16 waves/CU).
// Phase A: stage h1 rows in LDS (8 KB); 64 dots (2 rows x 2 nets x 16 outs),
//          4 lanes per dot with interleaved 16B K-chunks (conflict-free,
//          contiguous 64B per lane-quad), 2-level shuffle reduce.
// Phase B: y = (x-mu)/(exp(0.5*lv)+eps); last-step outputs.
// Phase C: h0' = elu(y @ W0^T + b0), 8 j-indices per thread, coalesced.
__global__ __launch_bounds__(256) void step2(
    const u16* __restrict__ h1, const u16* __restrict__ W2,
    const float* __restrict__ b2_mu, const float* __restrict__ b2_lv,
    const u16* __restrict__ W0,
    const float* __restrict__ b0_mu, const float* __restrict__ b0_lv,
    const float* __restrict__ x,
    u16* __restrict__ h0, float* __restrict__ out, int last) {
  __shared__ u16 sH[4 * 1032];      // [r*2+net][1024 (+8 pad)]
  __shared__ float sOut[2][32];
  __shared__ float sY[2][16];
  int tid = threadIdx.x;
  int b0g = blockIdx.x * 2;

  // stage 2 rows x 2 nets of h1 (8 KB), coalesced
  for (int i = 0; i < 2; ++i) {
    int q = i * 256 + tid;          // 8-elem chunk id, 0..511
    int s = q >> 7, wi = (q & 127) * 8;
    int net = s & 1, r = s >> 1;
    *(u16x8*)(sH + s * 1032 + wi) =
        *(const u16x8*)(h1 + (size_t)net * (Bb * Hh) +
                        (size_t)(b0g + r) * Hh + wi);
  }
  __syncthreads();

  // layer2: 64 dots of length 1024, 4 lanes/dot
  {
    int d = tid >> 2, c = tid & 3;  // dot id, K-chunk lane
    int r = d >> 5, o = d & 31, net = o >> 4, ir = o & 15;
    int s = r * 2 + net;
    const u16* hp = sH + s * 1032 + c * 8;
    const u16* wp = W2 + (size_t)(net * 16 + ir) * Hh + c * 8;
    float p = 0.f;
    for (int it = 0; it < 32; ++it) {
      u16x8 hv = *(const u16x8*)(hp + it * 32);
      u16x8 wv = *(const u16x8*)(wp + it * 32);
      for (int tt = 0; tt < 8; ++tt) p += bf2f(hv[tt]) * bf2f(wv[tt]);
    }
    p += __shfl_xor(p, 1);
    p += __shfl_xor(p, 2);
    if (c == 0) sOut[r][o] = p + (net ? b2_lv : b2_mu)[ir];
  }
  __syncthreads();

  // recurrence
  if (tid < 32) {
    int r = tid >> 4, d = tid & 15;
    int b = b0g + r;
    float mu = sOut[r][d];
    float ls = 0.5f * sOut[r][16 + d];
    float yn = (x[b * 16 + d] - mu) / (__expf(ls) + EPSV);
    sY[r][d] = yn;
    if (last) {
      out[b * 16 + d] = yn;
      float pp = ls;
      pp += __shfl_xor(pp, 1);
      pp += __shfl_xor(pp, 2);
      pp += __shfl_xor(pp, 4);
      pp += __shfl_xor(pp, 8);
      if (d == 0) out[Bb * 16 + b] = pp;
    }
  }
  __syncthreads();

  // layer0 -> next h0
  if (!last) {
    for (int it = 0; it < 8; ++it) {
      int jj = it * 256 + tid;      // 0..2047
      int net = jj >> 10, j = jj & 1023;
      u16x8 wa = *(const u16x8*)(W0 + jj * 16);
      u16x8 wb = *(const u16x8*)(W0 + jj * 16 + 8);
      float wk[16];
      for (int tt = 0; tt < 8; ++tt) {
        wk[tt] = bf2f(wa[tt]); wk[8 + tt] = bf2f(wb[tt]);
      }
      float bias = (net ? b0_lv : b0_mu)[j];
      u16* hp = h0 + (size_t)net * (Bb * Hh) + j;
      for (int r = 0; r < 2; ++r) {
        float a = bias;
        for (int k = 0; k < 16; ++k) a += sY[r][k] * wk[k];
        hp[(size_t)(b0g + r) * Hh] = f2bf(elu(a));
      }
    }
  }
}

// --------------------------- launch ----------------------------------------

extern "C" void kernel_launch(void* const* d_in, const int* in_sizes, int n_in,
                              void* d_out, int out_size, void* d_ws, size_t ws_size,
                              hipStream_t stream) {
  const float* x     = (const float*)d_in[0];
  const float* mu_v0 = (const float*)d_in[1];
  const float* mu_g0 = (const float*)d_in[2];
  const float* mu_b0 = (const float*)d_in[3];
  const float* mu_v1 = (const float*)d_in[4];
  const float* mu_g1 = (const float*)d_in[5];
  const float* mu_b1 = (const float*)d_in[6];
  const float* mu_v2 = (const float*)d_in[7];
  const float* mu_g2 = (const float*)d_in[8];
  const float* mu_b2 = (const float*)d_in[9];
  const float* lv_v0 = (const float*)d_in[10];
  const float* lv_g0 = (const float*)d_in[11];
  const float* lv_b0 = (const float*)d_in[12];
  const float* lv_v1 = (const float*)d_in[13];
  const float* lv_g1 = (const float*)d_in[14];
  const float* lv_b1 = (const float*)d_in[15];
  const float* lv_v2 = (const float*)d_in[16];
  const float* lv_g2 = (const float*)d_in[17];
  const float* lv_b2 = (const float*)d_in[18];

  char* ws = (char*)d_ws;
  u16* W1 = (u16*)(ws);                          // 4 MiB
  u16* W0 = (u16*)(ws + (4u << 20));             // 64 KiB
  u16* W2 = (u16*)(ws + (4u << 20) + 65536);     // 64 KiB
  u16* h0 = (u16*)(ws + (4u << 20) + 131072);    // 8 MiB
  u16* h1 = (u16*)(ws + (12u << 20) + 131072);   // 8 MiB

  prep_w0<<<8, 256, 0, stream>>>(mu_v0, mu_g0, lv_v0, lv_g0, W0);
  prep_w1<<<512, 256, 0, stream>>>(mu_v1, mu_g1, lv_v1, lv_g1, W1);
  prep_w2<<<8, 256, 0, stream>>>(mu_v2, mu_g2, lv_v2, lv_g2, W2);
  init_h0<<<16384, 256, 0, stream>>>(mu_b0, lv_b0, h0);

  for (int s = 0; s < 16; ++s) {
    gemm_l1<<<256, 512, 0, stream>>>(h0, W1, mu_b1, lv_b1, h1);
    step2<<<1024, 256, 0, stream>>>(h1, W2, mu_b2, lv_b2, W0, mu_b0,
                                    lv_b0, x, h0, (float*)d_out,
                                    s == 15 ? 1 : 0);
  }
}

// Round 3
// 541.017 us; speedup vs baseline: 2.9874x; 1.3243x over previous
//
#include <hip/hip_runtime.h>
#include <cstdint>
#include <cstddef>

// ---------------------------------------------------------------------------
// AFMADE block: 16-step autoregressive inversion of two 3-layer MADE MLPs.
// D=16, H=1024, B=2048.
//   prep_*   : bake mask * g * v/||v|| into bf16 weights (once per launch)
//   init_h0  : h0 = elu(b0)  (y starts at 0)
//   loop 16x : gemm_l1f (MFMA bf16, h1 = elu(h0 @ W1^T + b1) in-register,
//                        fused layer2 partial: part[net][b][nt][:] ; h1 never
//                        hits global memory)
//              step3    (reduce partials -> mu/lv, recurrence, layer0 -> h0)
// ---------------------------------------------------------------------------

#define Dd 16
#define Hh 1024
#define Bb 2048
#define EPSV 1e-12f

typedef unsigned short u16;
typedef __attribute__((ext_vector_type(4))) float f32x4;
typedef __attribute__((ext_vector_type(8))) short s16x8;
typedef __attribute__((ext_vector_type(4))) u16 u16x4;
typedef __attribute__((ext_vector_type(8))) u16 u16x8;

__device__ __forceinline__ u16 f2bf(float f) {
  union { float f; unsigned u; } v; v.f = f;
  unsigned u = v.u;
  unsigned r = (u + 0x7fffu + ((u >> 16) & 1u)) >> 16;  // RNE
  return (u16)r;
}
__device__ __forceinline__ float bf2f(u16 u) {
  union { unsigned u; float f; } v; v.u = ((unsigned)u) << 16;
  return v.f;
}
__device__ __forceinline__ float elu(float a) {
  return a > 0.f ? a : __expf(a) - 1.f;
}
__device__ __forceinline__ void gl_lds16(const u16* g, u16* l) {
  __builtin_amdgcn_global_load_lds(
      (const __attribute__((address_space(1))) void*)g,
      (__attribute__((address_space(3))) void*)l, 16, 0, 0);
}

// --------------------------- weight prep -----------------------------------

// W0[net][j][d] = m0 * g*v/||v||, m0: (j%15) >= d. One thread per (net,j).
__global__ __launch_bounds__(256) void prep_w0(
    const float* __restrict__ v_mu, const float* __restrict__ g_mu,
    const float* __restrict__ v_lv, const float* __restrict__ g_lv,
    u16* __restrict__ W0) {
  int idx = blockIdx.x * 256 + threadIdx.x;  // 0..2047
  int net = idx >> 10, j = idx & 1023;
  const float* v = (net ? v_lv : v_mu) + j * Dd;
  float vv[16]; float ss = 0.f;
  for (int k = 0; k < 16; ++k) { vv[k] = v[k]; ss += vv[k] * vv[k]; }
  float sc = ((net ? g_lv : g_mu)[j]) * rsqrtf(ss);
  int jm = j % 15;
  u16* o = W0 + idx * 16;
  for (int k = 0; k < 16; ++k) o[k] = f2bf((jm >= k) ? sc * vv[k] : 0.f);
}

// W1[net][j][k] = m1 * g*v/||v||, m1: (j%15) >= (k%15). One wave per row.
__global__ __launch_bounds__(256) void prep_w1(
    const float* __restrict__ v_mu, const float* __restrict__ g_mu,
    const float* __restrict__ v_lv, const float* __restrict__ g_lv,
    u16* __restrict__ W1) {
  int wid = blockIdx.x * 4 + (threadIdx.x >> 6);  // 0..2047
  int l = threadIdx.x & 63;
  int net = wid >> 10, j = wid & 1023;
  const float* v = (net ? v_lv : v_mu) + (size_t)j * Hh;
  f32x4 val[4]; float ss = 0.f;
  for (int ii = 0; ii < 4; ++ii) {
    val[ii] = *(const f32x4*)(v + ii * 256 + 4 * l);
    ss += val[ii][0]*val[ii][0] + val[ii][1]*val[ii][1]
        + val[ii][2]*val[ii][2] + val[ii][3]*val[ii][3];
  }
  for (int s = 32; s; s >>= 1) ss += __shfl_xor(ss, s);
  float sc = ((net ? g_lv : g_mu)[j]) * rsqrtf(ss);
  int jm = j % 15;
  u16* o = W1 + (size_t)wid * Hh;
  for (int ii = 0; ii < 4; ++ii) {
    int k0 = ii * 256 + 4 * l;
    u16x4 w;
    for (int t = 0; t < 4; ++t) {
      int k = k0 + t;
      w[t] = f2bf((jm >= (k % 15)) ? sc * val[ii][t] : 0.f);
    }
    *(u16x4*)(o + k0) = w;
  }
}

// W2[net][i][k] = m2 * g*v/||v||, m2: i > (k%15). One wave per row (32 rows).
__global__ __launch_bounds__(256) void prep_w2(
    const float* __restrict__ v_mu, const float* __restrict__ g_mu,
    const float* __restrict__ v_lv, const float* __restrict__ g_lv,
    u16* __restrict__ W2) {
  int wid = blockIdx.x * 4 + (threadIdx.x >> 6);  // 0..31
  int l = threadIdx.x & 63;
  int net = wid >> 4, i = wid & 15;
  const float* v = (net ? v_lv : v_mu) + (size_t)i * Hh;
  f32x4 val[4]; float ss = 0.f;
  for (int ii = 0; ii < 4; ++ii) {
    val[ii] = *(const f32x4*)(v + ii * 256 + 4 * l);
    ss += val[ii][0]*val[ii][0] + val[ii][1]*val[ii][1]
        + val[ii][2]*val[ii][2] + val[ii][3]*val[ii][3];
  }
  for (int s = 32; s; s >>= 1) ss += __shfl_xor(ss, s);
  float sc = ((net ? g_lv : g_mu)[i]) * rsqrtf(ss);
  u16* o = W2 + (size_t)wid * Hh;
  for (int ii = 0; ii < 4; ++ii) {
    int k0 = ii * 256 + 4 * l;
    u16x4 w;
    for (int t = 0; t < 4; ++t) {
      int k = k0 + t;
      w[t] = f2bf((i > (k % 15)) ? sc * val[ii][t] : 0.f);
    }
    *(u16x4*)(o + k0) = w;
  }
}

// --------------------------- init ------------------------------------------

// h0[net][b][j] = elu(b0[net][j])  (y == 0 at step 0)
__global__ __launch_bounds__(256) void init_h0(
    const float* __restrict__ b0_mu, const float* __restrict__ b0_lv,
    u16* __restrict__ h0) {
  int idx = blockIdx.x * 256 + threadIdx.x;  // over 2*2048*1024
  int j = idx & 1023;
  int net = idx >> 21;
  float b = (net ? b0_lv : b0_mu)[j];
  h0[idx] = f2bf(elu(b));
}

// --------------------------- layer1 GEMM + fused layer2 partial ------------
// Per net: M=2048, N=1024, K=1024. Tile 128x64, BK=64, 4 waves (2x2),
// wave tile 64x32 (4x2 frags), mfma_f32_16x16x32_bf16.
// grid = 2 nets * 16 mt * 16 nt = 512 blocks (2 blocks/CU), 256 threads.
// Epilogue: h1 tile -> LDS (stride 72), mini-GEMM vs W2 cols (4 MFMA/wave)
// -> part[net][m0+row][nt][i] fp32. h1 never stored to global.
__global__ __launch_bounds__(256) void gemm_l1f(
    const u16* __restrict__ h0, const u16* __restrict__ W1,
    const float* __restrict__ b1_mu, const float* __restrict__ b1_lv,
    const u16* __restrict__ W2,
    float* __restrict__ part) {
  __shared__ u16 sMem[128 * 64 + 64 * 64];  // 24 KiB: sA | sB ; reused as sH
  __shared__ u16 sW2b[16 * 72];             // W2 cols tile, padded stride
  u16* sA = sMem;
  u16* sB = sMem + 128 * 64;

  int bid = blockIdx.x;
  int net = bid >> 8;
  int t = bid & 255;
  int mt = t >> 4, nt = t & 15;
  int m0 = mt * 128, n0 = nt * 64;
  const u16* A = h0 + (size_t)net * (Bb * Hh);
  const u16* Bm = W1 + (size_t)net * (Hh * Hh);
  int tid = threadIdx.x;
  int l = tid & 63, w = tid >> 6;
  int wr = w >> 1, wc = w & 1;      // 2 x 2 wave grid
  int lr = l & 15, lk = l >> 4;
  f32x4 acc[4][2] = {};

  // stage W2 column tile (16 x 64) as bf16, padded stride 72
  for (int c = 0; c < 4; ++c) {
    int e = c * 256 + tid;          // 0..1023
    int i = e >> 6, col = e & 63;
    sW2b[i * 72 + col] = W2[(size_t)(net * 16 + i) * Hh + n0 + col];
  }

  for (int kt = 0; kt < 16; ++kt) {
    int kb = kt * 64;
    __syncthreads();
    for (int c = 0; c < 4; ++c) {   // A: 128 rows x 8 chunks
      int q = c * 256 + tid;
      int row = q >> 3, cc = q & 7;
      gl_lds16(A + (size_t)(m0 + row) * Hh + kb + cc * 8, sA + q * 8);
    }
    for (int c = 0; c < 2; ++c) {   // B: 64 rows x 8 chunks
      int q = c * 256 + tid;
      int row = q >> 3, cc = q & 7;
      gl_lds16(Bm + (size_t)(n0 + row) * Hh + kb + cc * 8, sB + q * 8);
    }
    __syncthreads();
    for (int kk = 0; kk < 2; ++kk) {
      int ko = kk * 32 + lk * 8;
      s16x8 af[4], bfr[2];
      for (int mi = 0; mi < 4; ++mi)
        af[mi] = *(const s16x8*)(sA + (wr * 64 + mi * 16 + lr) * 64 + ko);
      for (int ni = 0; ni < 2; ++ni)
        bfr[ni] = *(const s16x8*)(sB + (wc * 32 + ni * 16 + lr) * 64 + ko);
      for (int mi = 0; mi < 4; ++mi)
        for (int ni = 0; ni < 2; ++ni)
          acc[mi][ni] = __builtin_amdgcn_mfma_f32_16x16x32_bf16(
              af[mi], bfr[ni], acc[mi][ni], 0, 0, 0);
    }
  }

  // ---- epilogue: h1 tile to LDS (bf16, stride 72), then layer2 partial ----
  const float* b1 = net ? b1_lv : b1_mu;
  __syncthreads();                  // all MFMA consumed sA/sB
  u16* sH = sMem;                   // 128 x 72 = 18432 u16 <= 24K region
  for (int ni = 0; ni < 2; ++ni) {
    int col = wc * 32 + ni * 16 + lr;
    float bias = b1[n0 + col];
    for (int mi = 0; mi < 4; ++mi)
      for (int r = 0; r < 4; ++r) {
        int row = wr * 64 + mi * 16 + lk * 4 + r;
        sH[row * 72 + col] = f2bf(elu(acc[mi][ni][r] + bias));
      }
  }
  __syncthreads();

  // mini-GEMM: wave w handles h1 rows w*32..w*32+31 vs W2 tile (16 outs)
  {
    f32x4 acc2[2] = {};
    for (int kk = 0; kk < 2; ++kk) {
      int ko = kk * 32 + lk * 8;
      s16x8 bfr = *(const s16x8*)(sW2b + lr * 72 + ko);
      for (int mi = 0; mi < 2; ++mi) {
        s16x8 af = *(const s16x8*)(sH + (w * 32 + mi * 16 + lr) * 72 + ko);
        acc2[mi] = __builtin_amdgcn_mfma_f32_16x16x32_bf16(
            af, bfr, acc2[mi], 0, 0, 0);
      }
    }
    for (int mi = 0; mi < 2; ++mi)
      for (int r = 0; r < 4; ++r) {
        int row = m0 + w * 32 + mi * 16 + lk * 4 + r;
        part[((size_t)(net * Bb) + row) * 256 + nt * 16 + lr] = acc2[mi][r];
      }
  }
}

// --------------------------- partial reduce + recur + layer0 ---------------
// 2 batch rows per block, 1024 blocks x 256 threads.
__global__ __launch_bounds__(256) void step3(
    const float* __restrict__ part,
    const float* __restrict__ b2_mu, const float* __restrict__ b2_lv,
    const u16* __restrict__ W0,
    const float* __restrict__ b0_mu, const float* __restrict__ b0_lv,
    const float* __restrict__ x,
    u16* __restrict__ h0, float* __restrict__ out, int last) {
  __shared__ float sPart[4][260];   // [r*2+net][nt*16+i], padded
  __shared__ float sOut[2][32];
  __shared__ float sY[2][16];
  int tid = threadIdx.x;
  int b0g = blockIdx.x * 2;

  {
    int seg = tid >> 6, idx = (tid & 63) * 4;  // seg = r*2+net
    int r = seg >> 1, net = seg & 1;
    const float* src = part + ((size_t)(net * Bb) + b0g + r) * 256 + idx;
    *(f32x4*)&sPart[seg][idx] = *(const f32x4*)src;
  }
  __syncthreads();
  if (tid < 64) {
    int seg = tid >> 4, i = tid & 15;
    int r = seg >> 1, net = seg & 1;
    float s = 0.f;
    for (int ntc = 0; ntc < 16; ++ntc) s += sPart[seg][ntc * 16 + i];
    sOut[r][net * 16 + i] = s + (net ? b2_lv : b2_mu)[i];
  }
  __syncthreads();

  if (tid < 32) {
    int r = tid >> 4, d = tid & 15;
    int b = b0g + r;
    float mu = sOut[r][d];
    float ls = 0.5f * sOut[r][16 + d];
    float yn = (x[b * 16 + d] - mu) / (__expf(ls) + EPSV);
    sY[r][d] = yn;
    if (last) {
      out[b * 16 + d] = yn;
      float pp = ls;
      pp += __shfl_xor(pp, 1);
      pp += __shfl_xor(pp, 2);
      pp += __shfl_xor(pp, 4);
      pp += __shfl_xor(pp, 8);
      if (d == 0) out[Bb * 16 + b] = pp;
    }
  }
  __syncthreads();

  if (!last) {
    for (int it = 0; it < 8; ++it) {
      int jj = it * 256 + tid;      // 0..2047
      int net = jj >> 10, j = jj & 1023;
      u16x8 wa = *(const u16x8*)(W0 + jj * 16);
      u16x8 wb = *(const u16x8*)(W0 + jj * 16 + 8);
      float wk[16];
      for (int tt = 0; tt < 8; ++tt) {
        wk[tt] = bf2f(wa[tt]); wk[8 + tt] = bf2f(wb[tt]);
      }
      float bias = (net ? b0_lv : b0_mu)[j];
      u16* hp = h0 + (size_t)net * (Bb * Hh) + j;
      for (int r = 0; r < 2; ++r) {
        float a = bias;
        for (int k = 0; k < 16; ++k) a += sY[r][k] * wk[k];
        hp[(size_t)(b0g + r) * Hh] = f2bf(elu(a));
      }
    }
  }
}

// --------------------------- launch ----------------------------------------

extern "C" void kernel_launch(void* const* d_in, const int* in_sizes, int n_in,
                              void* d_out, int out_size, void* d_ws, size_t ws_size,
                              hipStream_t stream) {
  const float* x     = (const float*)d_in[0];
  const float* mu_v0 = (const float*)d_in[1];
  const float* mu_g0 = (const float*)d_in[2];
  const float* mu_b0 = (const float*)d_in[3];
  const float* mu_v1 = (const float*)d_in[4];
  const float* mu_g1 = (const float*)d_in[5];
  const float* mu_b1 = (const float*)d_in[6];
  const float* mu_v2 = (const float*)d_in[7];
  const float* mu_g2 = (const float*)d_in[8];
  const float* mu_b2 = (const float*)d_in[9];
  const float* lv_v0 = (const float*)d_in[10];
  const float* lv_g0 = (const float*)d_in[11];
  const float* lv_b0 = (const float*)d_in[12];
  const float* lv_v1 = (const float*)d_in[13];
  const float* lv_g1 = (const float*)d_in[14];
  const float* lv_b1 = (const float*)d_in[15];
  const float* lv_v2 = (const float*)d_in[16];
  const float* lv_g2 = (const float*)d_in[17];
  const float* lv_b2 = (const float*)d_in[18];

  char* ws = (char*)d_ws;
  u16*   W1   = (u16*)(ws);                          // 4 MiB
  u16*   W0   = (u16*)(ws + (4u << 20));             // 64 KiB
  u16*   W2   = (u16*)(ws + (4u << 20) + 65536);     // 64 KiB
  u16*   h0   = (u16*)(ws + (4u << 20) + 131072);    // 8 MiB
  float* part = (float*)(ws + (12u << 20) + 131072); // 4 MiB

  prep_w0<<<8, 256, 0, stream>>>(mu_v0, mu_g0, lv_v0, lv_g0, W0);
  prep_w1<<<512, 256, 0, stream>>>(mu_v1, mu_g1, lv_v1, lv_g1, W1);
  prep_w2<<<8, 256, 0, stream>>>(mu_v2, mu_g2, lv_v2, lv_g2, W2);
  init_h0<<<16384, 256, 0, stream>>>(mu_b0, lv_b0, h0);

  for (int s = 0; s < 16; ++s) {
    gemm_l1f<<<512, 256, 0, stream>>>(h0, W1, mu_b1, lv_b1, W2, part);
    step3<<<1024, 256, 0, stream>>>(part, mu_b2, lv_b2, W0, mu_b0,
                                    lv_b0, x, h0, (float*)d_out,
                                    s == 15 ? 1 : 0);
  }
}

// Round 5
// 541.013 us; speedup vs baseline: 2.9874x; 1.0000x over previous
//
#include <hip/hip_runtime.h>
#include <hip/hip_cooperative_groups.h>
#include <cstdint>
#include <cstddef>

namespace cg = cooperative_groups;

// ---------------------------------------------------------------------------
// AFMADE block: 16-step autoregressive inversion of two 3-layer MADE MLPs.
// D=16, H=1024, B=2048.
// Two execution paths, same math:
//   A) afmade_all: persistent cooperative kernel (512 blocks x 256 thr,
//      2 blocks/CU, LDS ~27.6 KB), grid.sync between phases.
//   B) fallback: R3-validated multi-kernel sequence.
// Path chosen by capture-safe occupancy/attribute queries (deterministic).
// ---------------------------------------------------------------------------

#define Dd 16
#define Hh 1024
#define Bb 2048
#define EPSV 1e-12f

typedef unsigned short u16;
typedef __attribute__((ext_vector_type(4))) float f32x4;
typedef __attribute__((ext_vector_type(8))) short s16x8;
typedef __attribute__((ext_vector_type(4))) u16 u16x4;
typedef __attribute__((ext_vector_type(8))) u16 u16x8;

__device__ __forceinline__ u16 f2bf(float f) {
  union { float f; unsigned u; } v; v.f = f;
  unsigned u = v.u;
  unsigned r = (u + 0x7fffu + ((u >> 16) & 1u)) >> 16;  // RNE
  return (u16)r;
}
__device__ __forceinline__ float bf2f(u16 u) {
  union { unsigned u; float f; } v; v.u = ((unsigned)u) << 16;
  return v.f;
}
__device__ __forceinline__ float elu(float a) {
  return a > 0.f ? a : __expf(a) - 1.f;
}
__device__ __forceinline__ void gl_lds16(const u16* g, u16* l) {
  __builtin_amdgcn_global_load_lds(
      (const __attribute__((address_space(1))) void*)g,
      (__attribute__((address_space(3))) void*)l, 16, 0, 0);
}

struct KParams {
  const float *x;
  const float *mu_v0, *mu_g0, *mu_b0, *mu_v1, *mu_g1, *mu_b1, *mu_v2, *mu_g2, *mu_b2;
  const float *lv_v0, *lv_g0, *lv_b0, *lv_v1, *lv_g1, *lv_b1, *lv_v2, *lv_g2, *lv_b2;
  u16 *W0, *W1, *W2, *h0;
  float *part, *out;
};

// ======================= cooperative fused kernel ==========================

__global__ __launch_bounds__(256, 2) void afmade_all(KParams p) {
  __shared__ __align__(16) u16 sMem[128 * 64 + 64 * 64];  // 24 KiB
  __shared__ u16 sW2b[16 * 72];
  __shared__ float sOut[4][32];
  __shared__ float sY[4][16];

  cg::grid_group grid = cg::this_grid();

  const int bid = blockIdx.x;        // 0..511
  const int tid = threadIdx.x;       // 0..255
  const int l = tid & 63, w = tid >> 6;

  // ---------------- prep phase ----------------
  {
    int wid = bid * 4 + w;           // W1 rows: one wave each (2048)
    int net = wid >> 10, j = wid & 1023;
    const float* v = (net ? p.lv_v1 : p.mu_v1) + (size_t)j * Hh;
    f32x4 val[4]; float ss = 0.f;
    for (int ii = 0; ii < 4; ++ii) {
      val[ii] = *(const f32x4*)(v + ii * 256 + 4 * l);
      ss += val[ii][0]*val[ii][0] + val[ii][1]*val[ii][1]
          + val[ii][2]*val[ii][2] + val[ii][3]*val[ii][3];
    }
    for (int s = 32; s; s >>= 1) ss += __shfl_xor(ss, s);
    float sc = ((net ? p.lv_g1 : p.mu_g1)[j]) * rsqrtf(ss);
    int jm = j % 15;
    u16* o = p.W1 + (size_t)wid * Hh;
    for (int ii = 0; ii < 4; ++ii) {
      int k0 = ii * 256 + 4 * l;
      u16x4 wv;
      for (int t = 0; t < 4; ++t) {
        int k = k0 + t;
        wv[t] = f2bf((jm >= (k % 15)) ? sc * val[ii][t] : 0.f);
      }
      *(u16x4*)(o + k0) = wv;
    }
  }
  if (bid < 8) {                     // W0: one thread per (net,j)
    int idx = bid * 256 + tid;
    int net = idx >> 10, j = idx & 1023;
    const float* v = (net ? p.lv_v0 : p.mu_v0) + j * Dd;
    float vv[16]; float ss = 0.f;
    for (int k = 0; k < 16; ++k) { vv[k] = v[k]; ss += vv[k] * vv[k]; }
    float sc = ((net ? p.lv_g0 : p.mu_g0)[j]) * rsqrtf(ss);
    int jm = j % 15;
    u16* o = p.W0 + idx * 16;
    for (int k = 0; k < 16; ++k) o[k] = f2bf((jm >= k) ? sc * vv[k] : 0.f);
  }
  if (bid >= 8 && bid < 16) {        // W2: one wave per row (32 rows)
    int wid = (bid - 8) * 4 + w;
    int net = wid >> 4, i = wid & 15;
    const float* v = (net ? p.lv_v2 : p.mu_v2) + (size_t)i * Hh;
    f32x4 val[4]; float ss = 0.f;
    for (int ii = 0; ii < 4; ++ii) {
      val[ii] = *(const f32x4*)(v + ii * 256 + 4 * l);
      ss += val[ii][0]*val[ii][0] + val[ii][1]*val[ii][1]
          + val[ii][2]*val[ii][2] + val[ii][3]*val[ii][3];
    }
    for (int s = 32; s; s >>= 1) ss += __shfl_xor(ss, s);
    float sc = ((net ? p.lv_g2 : p.mu_g2)[i]) * rsqrtf(ss);
    u16* o = p.W2 + (size_t)wid * Hh;
    for (int ii = 0; ii < 4; ++ii) {
      int k0 = ii * 256 + 4 * l;
      u16x4 wv;
      for (int t = 0; t < 4; ++t) {
        int k = k0 + t;
        wv[t] = f2bf((i > (k % 15)) ? sc * val[ii][t] : 0.f);
      }
      *(u16x4*)(o + k0) = wv;
    }
  }
  {                                  // h0 = elu(b0): 8192 elems per block
    for (int it = 0; it < 4; ++it) {
      int e = bid * 8192 + it * 2048 + tid * 8;
      int net = e >> 21;
      int j = e & 1023;
      const float* b0 = net ? p.lv_b0 : p.mu_b0;
      u16x8 hv;
      for (int t = 0; t < 8; ++t) hv[t] = f2bf(elu(b0[j + t]));
      *(u16x8*)(p.h0 + e) = hv;
    }
  }

  __threadfence();
  grid.sync();

  // ---------------- per-block geometry ----------------
  const int net = bid >> 8;
  const int t = bid & 255;
  const int mt = t >> 4, nt = t & 15;
  const int m0 = mt * 128, n0 = nt * 64;
  const u16* A = p.h0 + (size_t)net * (Bb * Hh);
  const u16* Bm = p.W1 + (size_t)net * (Hh * Hh);
  u16* sA = sMem;
  u16* sB = sMem + 128 * 64;
  const int wr = w >> 1, wc = w & 1;   // 2 x 2 wave grid
  const int lr = l & 15, lk = l >> 4;
  const float* b1 = net ? p.lv_b1 : p.mu_b1;
  const int b0g = bid * 4;             // step-phase batch rows

  // stage this block's W2 column tile once (persists in LDS)
  for (int c = 0; c < 4; ++c) {
    int e = c * 256 + tid;
    int i = e >> 6, col = e & 63;
    sW2b[i * 72 + col] = p.W2[(size_t)(net * 16 + i) * Hh + n0 + col];
  }

  for (int s = 0; s < 16; ++s) {
    const int last = (s == 15);

    // ---- GEMM phase (R3-validated single-buffer loop) ----
    f32x4 acc[4][2] = {};
    for (int kt = 0; kt < 16; ++kt) {
      int kb = kt * 64;
      __syncthreads();
      for (int c = 0; c < 4; ++c) {   // A: 128 rows x 8 chunks
        int q = c * 256 + tid, row = q >> 3, cc = q & 7;
        gl_lds16(A + (size_t)(m0 + row) * Hh + kb + cc * 8, sA + q * 8);
      }
      for (int c = 0; c < 2; ++c) {   // B: 64 rows x 8 chunks
        int q = c * 256 + tid, row = q >> 3, cc = q & 7;
        gl_lds16(Bm + (size_t)(n0 + row) * Hh + kb + cc * 8, sB + q * 8);
      }
      __syncthreads();
      for (int kk = 0; kk < 2; ++kk) {
        int ko = kk * 32 + lk * 8;
        s16x8 af[4], bfr[2];
        for (int mi = 0; mi < 4; ++mi)
          af[mi] = *(const s16x8*)(sA + (wr * 64 + mi * 16 + lr) * 64 + ko);
        for (int ni = 0; ni < 2; ++ni)
          bfr[ni] = *(const s16x8*)(sB + (wc * 32 + ni * 16 + lr) * 64 + ko);
        for (int mi = 0; mi < 4; ++mi)
          for (int ni = 0; ni < 2; ++ni)
            acc[mi][ni] = __builtin_amdgcn_mfma_f32_16x16x32_bf16(
                af[mi], bfr[ni], acc[mi][ni], 0, 0, 0);
      }
    }

    // epilogue: h1 tile -> LDS (stride 72), mini-GEMM vs W2 tile -> part
    {
      __syncthreads();
      u16* sH = sMem;                 // 128 x 72 = 9216 u16
      for (int ni = 0; ni < 2; ++ni) {
        int col = wc * 32 + ni * 16 + lr;
        float bias = b1[n0 + col];
        for (int mi = 0; mi < 4; ++mi)
          for (int r = 0; r < 4; ++r) {
            int row = wr * 64 + mi * 16 + lk * 4 + r;
            sH[row * 72 + col] = f2bf(elu(acc[mi][ni][r] + bias));
          }
      }
      __syncthreads();
      f32x4 acc2[2] = {};
      for (int kk = 0; kk < 2; ++kk) {
        int ko = kk * 32 + lk * 8;
        s16x8 bfr = *(const s16x8*)(sW2b + lr * 72 + ko);
        for (int mi = 0; mi < 2; ++mi) {
          s16x8 af = *(const s16x8*)(sH + (w * 32 + mi * 16 + lr) * 72 + ko);
          acc2[mi] = __builtin_amdgcn_mfma_f32_16x16x32_bf16(
              af, bfr, acc2[mi], 0, 0, 0);
        }
      }
      for (int mi = 0; mi < 2; ++mi)
        for (int r = 0; r < 4; ++r) {
          int row = m0 + w * 32 + mi * 16 + lk * 4 + r;
          p.part[((size_t)(net * Bb) + row) * 256 + nt * 16 + lr] = acc2[mi][r];
        }
    }

    __threadfence();
    grid.sync();

    // ---- step phase: 4 batch rows per block ----
    {
      float (*sPart)[260] = (float (*)[260])sMem;   // 8 x 260 fp32 = 8320 B
      for (int i = 0; i < 2; ++i) {
        int q = i * 256 + tid;          // 0..511
        int seg = q >> 6;               // r*2+net, r=0..3
        int idx = (q & 63) * 4;
        int r = seg >> 1, nn = seg & 1;
        const float* src = p.part + ((size_t)(nn * Bb) + b0g + r) * 256 + idx;
        *(f32x4*)&sPart[seg][idx] = *(const f32x4*)src;
      }
      __syncthreads();
      if (tid < 128) {
        int seg = tid >> 4, i = tid & 15;
        int r = seg >> 1, nn = seg & 1;
        float ssum = 0.f;
        for (int ntc = 0; ntc < 16; ++ntc) ssum += sPart[seg][ntc * 16 + i];
        sOut[r][nn * 16 + i] = ssum + (nn ? p.lv_b2 : p.mu_b2)[i];
      }
      __syncthreads();
      if (tid < 64) {
        int r = tid >> 4, d = tid & 15;
        int b = b0g + r;
        float mu = sOut[r][d];
        float ls = 0.5f * sOut[r][16 + d];
        float yn = (p.x[b * 16 + d] - mu) / (__expf(ls) + EPSV);
        sY[r][d] = yn;
        if (last) {
          p.out[b * 16 + d] = yn;
          float pp = ls;
          pp += __shfl_xor(pp, 1);
          pp += __shfl_xor(pp, 2);
          pp += __shfl_xor(pp, 4);
          pp += __shfl_xor(pp, 8);
          if (d == 0) p.out[Bb * 16 + b] = pp;
        }
      }
      __syncthreads();
      if (!last) {
        for (int it = 0; it < 8; ++it) {
          int nj = it * 256 + tid;      // 0..2047
          int nn = nj >> 10, j = nj & 1023;
          u16x8 wa = *(const u16x8*)(p.W0 + nj * 16);
          u16x8 wb = *(const u16x8*)(p.W0 + nj * 16 + 8);
          float wk[16];
          for (int tt = 0; tt < 8; ++tt) {
            wk[tt] = bf2f(wa[tt]); wk[8 + tt] = bf2f(wb[tt]);
          }
          float bias = (nn ? p.lv_b0 : p.mu_b0)[j];
          u16* hp = p.h0 + (size_t)nn * (Bb * Hh) + j;
          for (int r = 0; r < 4; ++r) {
            float a = bias;
            for (int k = 0; k < 16; ++k) a += sY[r][k] * wk[k];
            hp[(size_t)(b0g + r) * Hh] = f2bf(elu(a));
          }
        }
      }
    }

    __threadfence();
    grid.sync();
  }
}

// ======================= fallback kernels (R3, validated) ==================

__global__ __launch_bounds__(256) void prep_w0(
    const float* __restrict__ v_mu, const float* __restrict__ g_mu,
    const float* __restrict__ v_lv, const float* __restrict__ g_lv,
    u16* __restrict__ W0) {
  int idx = blockIdx.x * 256 + threadIdx.x;
  int net = idx >> 10, j = idx & 1023;
  const float* v = (net ? v_lv : v_mu) + j * Dd;
  float vv[16]; float ss = 0.f;
  for (int k = 0; k < 16; ++k) { vv[k] = v[k]; ss += vv[k] * vv[k]; }
  float sc = ((net ? g_lv : g_mu)[j]) * rsqrtf(ss);
  int jm = j % 15;
  u16* o = W0 + idx * 16;
  for (int k = 0; k < 16; ++k) o[k] = f2bf((jm >= k) ? sc * vv[k] : 0.f);
}

__global__ __launch_bounds__(256) void prep_w1(
    const float* __restrict__ v_mu, const float* __restrict__ g_mu,
    const float* __restrict__ v_lv, const float* __restrict__ g_lv,
    u16* __restrict__ W1) {
  int wid = blockIdx.x * 4 + (threadIdx.x >> 6);
  int l = threadIdx.x & 63;
  int net = wid >> 10, j = wid & 1023;
  const float* v = (net ? v_lv : v_mu) + (size_t)j * Hh;
  f32x4 val[4]; float ss = 0.f;
  for (int ii = 0; ii < 4; ++ii) {
    val[ii] = *(const f32x4*)(v + ii * 256 + 4 * l);
    ss += val[ii][0]*val[ii][0] + val[ii][1]*val[ii][1]
        + val[ii][2]*val[ii][2] + val[ii][3]*val[ii][3];
  }
  for (int s = 32; s; s >>= 1) ss += __shfl_xor(ss, s);
  float sc = ((net ? g_lv : g_mu)[j]) * rsqrtf(ss);
  int jm = j % 15;
  u16* o = W1 + (size_t)wid * Hh;
  for (int ii = 0; ii < 4; ++ii) {
    int k0 = ii * 256 + 4 * l;
    u16x4 wv;
    for (int t = 0; t < 4; ++t) {
      int k = k0 + t;
      wv[t] = f2bf((jm >= (k % 15)) ? sc * val[ii][t] : 0.f);
    }
    *(u16x4*)(o + k0) = wv;
  }
}

__global__ __launch_bounds__(256) void prep_w2(
    const float* __restrict__ v_mu, const float* __restrict__ g_mu,
    const float* __restrict__ v_lv, const float* __restrict__ g_lv,
    u16* __restrict__ W2) {
  int wid = blockIdx.x * 4 + (threadIdx.x >> 6);
  int l = threadIdx.x & 63;
  int net = wid >> 4, i = wid & 15;
  const float* v = (net ? v_lv : v_mu) + (size_t)i * Hh;
  f32x4 val[4]; float ss = 0.f;
  for (int ii = 0; ii < 4; ++ii) {
    val[ii] = *(const f32x4*)(v + ii * 256 + 4 * l);
    ss += val[ii][0]*val[ii][0] + val[ii][1]*val[ii][1]
        + val[ii][2]*val[ii][2] + val[ii][3]*val[ii][3];
  }
  for (int s = 32; s; s >>= 1) ss += __shfl_xor(ss, s);
  float sc = ((net ? g_lv : g_mu)[i]) * rsqrtf(ss);
  u16* o = W2 + (size_t)wid * Hh;
  for (int ii = 0; ii < 4; ++ii) {
    int k0 = ii * 256 + 4 * l;
    u16x4 wv;
    for (int t = 0; t < 4; ++t) {
      int k = k0 + t;
      wv[t] = f2bf((i > (k % 15)) ? sc * val[ii][t] : 0.f);
    }
    *(u16x4*)(o + k0) = wv;
  }
}

__global__ __launch_bounds__(256) void init_h0(
    const float* __restrict__ b0_mu, const float* __restrict__ b0_lv,
    u16* __restrict__ h0) {
  int idx = blockIdx.x * 256 + threadIdx.x;
  int j = idx & 1023;
  int net = idx >> 21;
  float b = (net ? b0_lv : b0_mu)[j];
  h0[idx] = f2bf(elu(b));
}

__global__ __launch_bounds__(256) void gemm_l1f(
    const u16* __restrict__ h0, const u16* __restrict__ W1,
    const float* __restrict__ b1_mu, const float* __restrict__ b1_lv,
    const u16* __restrict__ W2,
    float* __restrict__ part) {
  __shared__ u16 sMem[128 * 64 + 64 * 64];
  __shared__ u16 sW2b[16 * 72];
  u16* sA = sMem;
  u16* sB = sMem + 128 * 64;

  int bid = blockIdx.x;
  int net = bid >> 8;
  int t = bid & 255;
  int mt = t >> 4, nt = t & 15;
  int m0 = mt * 128, n0 = nt * 64;
  const u16* A = h0 + (size_t)net * (Bb * Hh);
  const u16* Bm = W1 + (size_t)net * (Hh * Hh);
  int tid = threadIdx.x;
  int l = tid & 63, w = tid >> 6;
  int wr = w >> 1, wc = w & 1;
  int lr = l & 15, lk = l >> 4;
  f32x4 acc[4][2] = {};

  for (int c = 0; c < 4; ++c) {
    int e = c * 256 + tid;
    int i = e >> 6, col = e & 63;
    sW2b[i * 72 + col] = W2[(size_t)(net * 16 + i) * Hh + n0 + col];
  }

  for (int kt = 0; kt < 16; ++kt) {
    int kb = kt * 64;
    __syncthreads();
    for (int c = 0; c < 4; ++c) {
      int q = c * 256 + tid, row = q >> 3, cc = q & 7;
      gl_lds16(A + (size_t)(m0 + row) * Hh + kb + cc * 8, sA + q * 8);
    }
    for (int c = 0; c < 2; ++c) {
      int q = c * 256 + tid, row = q >> 3, cc = q & 7;
      gl_lds16(Bm + (size_t)(n0 + row) * Hh + kb + cc * 8, sB + q * 8);
    }
    __syncthreads();
    for (int kk = 0; kk < 2; ++kk) {
      int ko = kk * 32 + lk * 8;
      s16x8 af[4], bfr[2];
      for (int mi = 0; mi < 4; ++mi)
        af[mi] = *(const s16x8*)(sA + (wr * 64 + mi * 16 + lr) * 64 + ko);
      for (int ni = 0; ni < 2; ++ni)
        bfr[ni] = *(const s16x8*)(sB + (wc * 32 + ni * 16 + lr) * 64 + ko);
      for (int mi = 0; mi < 4; ++mi)
        for (int ni = 0; ni < 2; ++ni)
          acc[mi][ni] = __builtin_amdgcn_mfma_f32_16x16x32_bf16(
              af[mi], bfr[ni], acc[mi][ni], 0, 0, 0);
    }
  }

  const float* b1 = net ? b1_lv : b1_mu;
  __syncthreads();
  u16* sH = sMem;
  for (int ni = 0; ni < 2; ++ni) {
    int col = wc * 32 + ni * 16 + lr;
    float bias = b1[n0 + col];
    for (int mi = 0; mi < 4; ++mi)
      for (int r = 0; r < 4; ++r) {
        int row = wr * 64 + mi * 16 + lk * 4 + r;
        sH[row * 72 + col] = f2bf(elu(acc[mi][ni][r] + bias));
      }
  }
  __syncthreads();

  {
    f32x4 acc2[2] = {};
    for (int kk = 0; kk < 2; ++kk) {
      int ko = kk * 32 + lk * 8;
      s16x8 bfr = *(const s16x8*)(sW2b + lr * 72 + ko);
      for (int mi = 0; mi < 2; ++mi) {
        s16x8 af = *(const s16x8*)(sH + (w * 32 + mi * 16 + lr) * 72 + ko);
        acc2[mi] = __builtin_amdgcn_mfma_f32_16x16x32_bf16(
            af, bfr, acc2[mi], 0, 0, 0);
      }
    }
    for (int mi = 0; mi < 2; ++mi)
      for (int r = 0; r < 4; ++r) {
        int row = m0 + w * 32 + mi * 16 + lk * 4 + r;
        part[((size_t)(net * Bb) + row) * 256 + nt * 16 + lr] = acc2[mi][r];
      }
  }
}

__global__ __launch_bounds__(256) void step3(
    const float* __restrict__ part,
    const float* __restrict__ b2_mu, const float* __restrict__ b2_lv,
    const u16* __restrict__ W0,
    const float* __restrict__ b0_mu, const float* __restrict__ b0_lv,
    const float* __restrict__ x,
    u16* __restrict__ h0, float* __restrict__ out, int last) {
  __shared__ float sPart[4][260];
  __shared__ float sOut[2][32];
  __shared__ float sY[2][16];
  int tid = threadIdx.x;
  int b0g = blockIdx.x * 2;

  {
    int seg = tid >> 6, idx = (tid & 63) * 4;
    int r = seg >> 1, net = seg & 1;
    const float* src = part + ((size_t)(net * Bb) + b0g + r) * 256 + idx;
    *(f32x4*)&sPart[seg][idx] = *(const f32x4*)src;
  }
  __syncthreads();
  if (tid < 64) {
    int seg = tid >> 4, i = tid & 15;
    int r = seg >> 1, net = seg & 1;
    float s = 0.f;
    for (int ntc = 0; ntc < 16; ++ntc) s += sPart[seg][ntc * 16 + i];
    sOut[r][net * 16 + i] = s + (net ? b2_lv : b2_mu)[i];
  }
  __syncthreads();

  if (tid < 32) {
    int r = tid >> 4, d = tid & 15;
    int b = b0g + r;
    float mu = sOut[r][d];
    float ls = 0.5f * sOut[r][16 + d];
    float yn = (x[b * 16 + d] - mu) / (__expf(ls) + EPSV);
    sY[r][d] = yn;
    if (last) {
      out[b * 16 + d] = yn;
      float pp = ls;
      pp += __shfl_xor(pp, 1);
      pp += __shfl_xor(pp, 2);
      pp += __shfl_xor(pp, 4);
      pp += __shfl_xor(pp, 8);
      if (d == 0) out[Bb * 16 + b] = pp;
    }
  }
  __syncthreads();

  if (!last) {
    for (int it = 0; it < 8; ++it) {
      int jj = it * 256 + tid;
      int net = jj >> 10, j = jj & 1023;
      u16x8 wa = *(const u16x8*)(W0 + jj * 16);
      u16x8 wb = *(const u16x8*)(W0 + jj * 16 + 8);
      float wk[16];
      for (int tt = 0; tt < 8; ++tt) {
        wk[tt] = bf2f(wa[tt]); wk[8 + tt] = bf2f(wb[tt]);
      }
      float bias = (net ? b0_lv : b0_mu)[j];
      u16* hp = h0 + (size_t)net * (Bb * Hh) + j;
      for (int r = 0; r < 2; ++r) {
        float a = bias;
        for (int k = 0; k < 16; ++k) a += sY[r][k] * wk[k];
        hp[(size_t)(b0g + r) * Hh] = f2bf(elu(a));
      }
    }
  }
}

// --------------------------- launch ----------------------------------------

static void launch_fallback(const KParams& p, hipStream_t stream) {
  prep_w0<<<8, 256, 0, stream>>>(p.mu_v0, p.mu_g0, p.lv_v0, p.lv_g0, p.W0);
  prep_w1<<<512, 256, 0, stream>>>(p.mu_v1, p.mu_g1, p.lv_v1, p.lv_g1, p.W1);
  prep_w2<<<8, 256, 0, stream>>>(p.mu_v2, p.mu_g2, p.lv_v2, p.lv_g2, p.W2);
  init_h0<<<16384, 256, 0, stream>>>(p.mu_b0, p.lv_b0, p.h0);
  for (int s = 0; s < 16; ++s) {
    gemm_l1f<<<512, 256, 0, stream>>>(p.h0, p.W1, p.mu_b1, p.lv_b1, p.W2,
                                      p.part);
    step3<<<1024, 256, 0, stream>>>(p.part, p.mu_b2, p.lv_b2, p.W0, p.mu_b0,
                                    p.lv_b0, p.x, p.h0, p.out,
                                    s == 15 ? 1 : 0);
  }
}

extern "C" void kernel_launch(void* const* d_in, const int* in_sizes, int n_in,
                              void* d_out, int out_size, void* d_ws, size_t ws_size,
                              hipStream_t stream) {
  char* ws = (char*)d_ws;
  KParams p;
  p.x     = (const float*)d_in[0];
  p.mu_v0 = (const float*)d_in[1];
  p.mu_g0 = (const float*)d_in[2];
  p.mu_b0 = (const float*)d_in[3];
  p.mu_v1 = (const float*)d_in[4];
  p.mu_g1 = (const float*)d_in[5];
  p.mu_b1 = (const float*)d_in[6];
  p.mu_v2 = (const float*)d_in[7];
  p.mu_g2 = (const float*)d_in[8];
  p.mu_b2 = (const float*)d_in[9];
  p.lv_v0 = (const float*)d_in[10];
  p.lv_g0 = (const float*)d_in[11];
  p.lv_b0 = (const float*)d_in[12];
  p.lv_v1 = (const float*)d_in[13];
  p.lv_g1 = (const float*)d_in[14];
  p.lv_b1 = (const float*)d_in[15];
  p.lv_v2 = (const float*)d_in[16];
  p.lv_g2 = (const float*)d_in[17];
  p.lv_b2 = (const float*)d_in[18];

  p.W1   = (u16*)(ws);                          // 4 MiB
  p.W0   = (u16*)(ws + (4u << 20));             // 64 KiB
  p.W2   = (u16*)(ws + (4u << 20) + 65536);     // 64 KiB
  p.h0   = (u16*)(ws + (4u << 20) + 131072);    // 8 MiB
  p.part = (float*)(ws + (12u << 20) + 131072); // 4 MiB
  p.out  = (float*)d_out;

  // Capture-safe, deterministic path selection.
  int coop_attr = 0, maxb = 0, dev = 0;
  bool use_coop = false;
  if (hipGetDevice(&dev) == hipSuccess &&
      hipDeviceGetAttribute(&coop_attr, hipDeviceAttributeCooperativeLaunch,
                            dev) == hipSuccess &&
      coop_attr &&
      hipOccupancyMaxActiveBlocksPerMultiprocessor(
          &maxb, (const void*)afmade_all, 256, 0) == hipSuccess &&
      maxb >= 2) {
    use_coop = true;
  }

  if (use_coop) {
    KParams pl = p;
    void* kargs[] = {&pl};
    hipError_t e = hipLaunchCooperativeKernel((void*)afmade_all, dim3(512),
                                              dim3(256), kargs, 0, stream);
    if (e == hipSuccess) return;
  }
  launch_fallback(p, stream);
}